// Round 2
// baseline (1247.146 us; speedup 1.0000x reference)
//
#include <hip/hip_runtime.h>

#define AS1 __attribute__((address_space(1)))
#define AS3 __attribute__((address_space(3)))

typedef unsigned short ushort_t;
typedef __attribute__((ext_vector_type(8))) short short8;
typedef __attribute__((ext_vector_type(4))) float floatx4;

__device__ __forceinline__ float bf2f(ushort_t h) {
    return __uint_as_float(((unsigned int)h) << 16);
}
__device__ __forceinline__ ushort_t f2bf(float f) {
    unsigned int u = __float_as_uint(f);
    u += 0x7fffu + ((u >> 16) & 1u);   // RNE
    return (ushort_t)(u >> 16);
}

// fp32 -> bf16 cast, 4 elems/thread
__global__ __launch_bounds__(256) void cast_f2b(const float* __restrict__ in,
                                                ushort_t* __restrict__ out, int n4)
{
    int i = blockIdx.x * 256 + threadIdx.x;
    if (i >= n4) return;
    float4 v = ((const float4*)in)[i];
    ushort_t o0 = f2bf(v.x), o1 = f2bf(v.y), o2 = f2bf(v.z), o3 = f2bf(v.w);
    ((ushort4*)out)[i] = make_ushort4(o0, o1, o2, o3);
}

// C[m,n] = sum_k A[m,k]*B[n,k];  A: M x lda bf16, B: N x ldb bf16.
// 128x128 tile, BK=32, 4 waves, each wave 64x64 (4x4 MFMA 16x16x32 tiles).
// MODE 0: cols<2048 -> outH (xi bf16), cols>=2048 -> outH2 (z bf16)
// MODE 1: bf16 store col<Nact (dbl)
// MODE 2: softplus(acc + biasF[col]) -> outF fp32 (dt)
// MODE 3: fp32 store col<Nact (final output)
template <int MODE>
__global__ __launch_bounds__(256) void gemm_bt(
    const ushort_t* __restrict__ A, int lda,
    const ushort_t* __restrict__ B, int ldb,
    int K, int Nact, int ldc,
    float* __restrict__ outF, ushort_t* __restrict__ outH,
    ushort_t* __restrict__ outH2, const float* __restrict__ biasF)
{
    constexpr int BM = 128, BN = 128, BK = 32;
    __shared__ ushort_t sA[BM * BK];
    __shared__ ushort_t sB[BN * BK];
    const int tid  = threadIdx.x;
    const int m0   = blockIdx.x * BM;
    const int n0   = blockIdx.y * BN;
    const int lane = tid & 63, wave = tid >> 6;
    const int wm   = (wave & 1) * 64, wn = (wave >> 1) * 64;
    const int lm   = lane & 15, quad = lane >> 4;

    floatx4 acc[4][4];
#pragma unroll
    for (int i = 0; i < 4; ++i)
#pragma unroll
        for (int j = 0; j < 4; ++j)
            acc[i][j] = (floatx4){0.f, 0.f, 0.f, 0.f};

    for (int k0 = 0; k0 < K; k0 += BK) {
        __syncthreads();
#pragma unroll
        for (int r = 0; r < 2; ++r) {
            int q   = r * 256 + tid;
            int row = q >> 2;
            int c8  = (q & 3) * 8;
            const ushort_t* gA = A + (size_t)(m0 + row) * lda + (k0 + c8);
            __builtin_amdgcn_global_load_lds((const AS1 void*)gA, (AS3 void*)(&sA[q * 8]), 16, 0, 0);
            int rowB = n0 + row;
            if (rowB >= Nact) rowB = Nact - 1;   // clamp; garbage cols discarded in epilogue
            const ushort_t* gB = B + (size_t)rowB * ldb + (k0 + c8);
            __builtin_amdgcn_global_load_lds((const AS1 void*)gB, (AS3 void*)(&sB[q * 8]), 16, 0, 0);
        }
        __syncthreads();

        short8 af[4], bfr[4];
#pragma unroll
        for (int i = 0; i < 4; ++i)
            af[i] = *(const short8*)&sA[(wm + i * 16 + lm) * BK + quad * 8];
#pragma unroll
        for (int j = 0; j < 4; ++j)
            bfr[j] = *(const short8*)&sB[(wn + j * 16 + lm) * BK + quad * 8];
#pragma unroll
        for (int i = 0; i < 4; ++i)
#pragma unroll
            for (int j = 0; j < 4; ++j)
                acc[i][j] = __builtin_amdgcn_mfma_f32_16x16x32_bf16(af[i], bfr[j], acc[i][j], 0, 0, 0);
    }

#pragma unroll
    for (int i = 0; i < 4; ++i) {
#pragma unroll
        for (int j = 0; j < 4; ++j) {
#pragma unroll
            for (int r = 0; r < 4; ++r) {
                int row = m0 + wm + i * 16 + quad * 4 + r;
                int col = n0 + wn + j * 16 + lm;
                float v = acc[i][j][r];
                if (MODE == 0) {
                    if (col < 2048) outH[(size_t)row * 2048 + col] = f2bf(v);
                    else            outH2[(size_t)row * 2048 + (col - 2048)] = f2bf(v);
                } else if (MODE == 1) {
                    if (col < Nact) outH[(size_t)row * ldc + col] = f2bf(v);
                } else if (MODE == 2) {
                    if (col < Nact) {
                        float x  = v + biasF[col];
                        float sp = (x > 20.f) ? x : log1pf(__expf(x));
                        outF[(size_t)row * ldc + col] = sp;
                    }
                } else {
                    if (col < Nact) outF[(size_t)row * ldc + col] = v;
                }
            }
        }
    }
}

// u = silu(depthwise_causal_conv4(xi) + conv_b), bf16 in/out; weights fp32
__global__ __launch_bounds__(256) void conv_silu_k(
    const ushort_t* __restrict__ xi, const float* __restrict__ conv_w,
    const float* __restrict__ conv_b, ushort_t* __restrict__ u)
{
    int idx = blockIdx.x * 256 + threadIdx.x;     // (b*L + l)*2048 + c
    int c   = idx & 2047;
    int bl  = idx >> 11;
    int l   = bl & 2047;
    float acc = conv_b[c];
#pragma unroll
    for (int k = 0; k < 4; ++k) {
        int ll = l - 3 + k;
        if (ll >= 0)
            acc += bf2f(xi[(size_t)(bl - 3 + k) * 2048 + c]) * conv_w[c * 4 + k];
    }
    float s = acc / (1.f + __expf(-acc));
    u[idx] = f2bf(s);
}

// Selective scan + D-skip + SiLU(z) gating. thread=(channel, state):
// block = 16 channels x 16 states; grid = 4 batches * 128 channel-blocks.
// y overwrites z in place (bf16).
__global__ __launch_bounds__(256) void scan_k(
    const float* __restrict__ dt, const ushort_t* __restrict__ u,
    const ushort_t* __restrict__ dbl, ushort_t* zy,
    const float* __restrict__ A_log, const float* __restrict__ D_skip)
{
    constexpr int L = 2048;
    const int tid = threadIdx.x;
    const int s   = tid & 15;
    const int cl  = tid >> 4;
    const int b   = blockIdx.x >> 7;
    const int c   = ((blockIdx.x & 127) << 4) + cl;
    const float As  = -__expf(A_log[c * 16 + s]);
    const float Dsk = D_skip[c];
    const size_t baseBL = (size_t)b * L;

    float h = 0.f;
    // software pipeline: prefetch t+1 while computing t
    size_t rb = baseBL;
    float dtv = dt[rb * 2048 + c];
    float uv  = bf2f(u[rb * 2048 + c]);
    float Bv  = bf2f(dbl[rb * 96 + 64 + s]);
    float Cv  = bf2f(dbl[rb * 96 + 80 + s]);
    float zv  = bf2f(zy[rb * 2048 + c]);

    for (int t = 0; t < L; ++t) {
        int tn = (t + 1 < L) ? (t + 1) : (L - 1);
        size_t rn = baseBL + tn;
        float dtn = dt[rn * 2048 + c];
        float un  = bf2f(u[rn * 2048 + c]);
        float Bn  = bf2f(dbl[rn * 96 + 64 + s]);
        float Cn  = bf2f(dbl[rn * 96 + 80 + s]);
        float zn  = bf2f(zy[rn * 2048 + c]);

        float dA = __expf(dtv * As);
        h = fmaf(h, dA, dtv * uv * Bv);
        float p = h * Cv;
        p += __shfl_xor(p, 1, 16);
        p += __shfl_xor(p, 2, 16);
        p += __shfl_xor(p, 4, 16);
        p += __shfl_xor(p, 8, 16);
        float g  = zv / (1.f + __expf(-zv));
        float yv = (p + uv * Dsk) * g;
        if (s == 0)
            zy[(baseBL + t) * 2048 + c] = f2bf(yv);

        dtv = dtn; uv = un; Bv = Bn; Cv = Cn; zv = zn;
    }
}

extern "C" void kernel_launch(void* const* d_in, const int* in_sizes, int n_in,
                              void* d_out, int out_size, void* d_ws, size_t ws_size,
                              hipStream_t stream)
{
    const float* x      = (const float*)d_in[0];   // (4,2048,1024)
    const float* W_in   = (const float*)d_in[1];   // (4096,1024)
    const float* conv_w = (const float*)d_in[2];   // (2048,4)
    const float* conv_b = (const float*)d_in[3];   // (2048,)
    const float* W_xp   = (const float*)d_in[4];   // (96,2048)
    const float* W_dt   = (const float*)d_in[5];   // (2048,64)
    const float* b_dt   = (const float*)d_in[6];   // (2048,)
    const float* A_log  = (const float*)d_in[7];   // (2048,16)
    const float* D_skip = (const float*)d_in[8];   // (2048,)
    const float* W_out  = (const float*)d_in[9];   // (1024,2048)

    char* ws = (char*)d_ws;
    const size_t MB = 1024 * 1024;
    // Region 0 (0..64MB): xi bf16 (32MB) + xw (16MB) + Wib (8MB) during phase 1;
    //                      reused as dt fp32 (64MB) from GEMM4 on (xi/xw/Wib dead).
    ushort_t* xi  = (ushort_t*)(ws);
    ushort_t* xw  = (ushort_t*)(ws + 32 * MB);
    ushort_t* Wib = (ushort_t*)(ws + 48 * MB);
    float*    dt  = (float*)(ws);
    ushort_t* z   = (ushort_t*)(ws + 64 * MB);    // 32MB
    ushort_t* u   = (ushort_t*)(ws + 96 * MB);    // 32MB
    ushort_t* dbl = (ushort_t*)(ws + 128 * MB);   // 1.5MB
    ushort_t* Wxb = (ushort_t*)(ws + 130 * MB);   // 0.375MB
    ushort_t* Wdb = (ushort_t*)(ws + 131 * MB);   // 0.25MB
    ushort_t* Wob = (ushort_t*)(ws + 132 * MB);   // 4MB

    // 0) fp32 -> bf16 casts for GEMM operands
    cast_f2b<<<8192, 256, 0, stream>>>(x, xw, 2097152);       // 8.4M elems
    cast_f2b<<<4096, 256, 0, stream>>>(W_in, Wib, 1048576);   // 4.2M
    cast_f2b<<<192, 256, 0, stream>>>(W_xp, Wxb, 49152);      // 196608
    cast_f2b<<<128, 256, 0, stream>>>(W_dt, Wdb, 32768);      // 131072
    cast_f2b<<<2048, 256, 0, stream>>>(W_out, Wob, 524288);   // 2.1M

    // 1) xz = x @ W_in^T : M=8192, N=4096, K=1024 -> xi bf16 | z bf16
    gemm_bt<0><<<dim3(64, 32), 256, 0, stream>>>(xw, 1024, Wib, 1024, 1024, 4096, 2048,
                                                 nullptr, xi, z, nullptr);
    // 2) u = silu(conv(xi)+b)
    conv_silu_k<<<65536, 256, 0, stream>>>(xi, conv_w, conv_b, u);
    // 3) dbl = u @ W_xproj^T : M=8192, N=96(pad 128), K=2048 -> bf16
    gemm_bt<1><<<dim3(64, 1), 256, 0, stream>>>(u, 2048, Wxb, 2048, 2048, 96, 96,
                                                nullptr, dbl, nullptr, nullptr);
    // 4) dt = softplus(dbl[:, :64] @ W_dt^T + b_dt) : M=8192, N=2048, K=64 -> fp32 (overlays xi)
    gemm_bt<2><<<dim3(64, 16), 256, 0, stream>>>(dbl, 96, Wdb, 64, 64, 2048, 2048,
                                                 dt, nullptr, nullptr, b_dt);
    // 5) selective scan + gating; y overwrites z (bf16)
    scan_k<<<512, 256, 0, stream>>>(dt, u, dbl, z, A_log, D_skip);
    // 6) out = y @ W_out^T : M=8192, N=1024, K=2048 -> fp32 d_out
    gemm_bt<3><<<dim3(64, 8), 256, 0, stream>>>(z, 2048, Wob, 2048, 2048, 1024, 1024,
                                                (float*)d_out, nullptr, nullptr, nullptr);
}

// Round 3
// 1001.643 us; speedup vs baseline: 1.2451x; 1.2451x over previous
//
#include <hip/hip_runtime.h>

#define AS1 __attribute__((address_space(1)))
#define AS3 __attribute__((address_space(3)))

typedef unsigned short ushort_t;
typedef __attribute__((ext_vector_type(8))) short short8;
typedef __attribute__((ext_vector_type(4))) float floatx4;

__device__ __forceinline__ float bf2f(ushort_t h) {
    return __uint_as_float(((unsigned int)h) << 16);
}
__device__ __forceinline__ ushort_t f2bf(float f) {
    unsigned int u = __float_as_uint(f);
    u += 0x7fffu + ((u >> 16) & 1u);   // RNE
    return (ushort_t)(u >> 16);
}

// fp32 -> bf16 cast, 4 elems/thread
__global__ __launch_bounds__(256) void cast_f2b(const float* __restrict__ in,
                                                ushort_t* __restrict__ out, int n4)
{
    int i = blockIdx.x * 256 + threadIdx.x;
    if (i >= n4) return;
    float4 v = ((const float4*)in)[i];
    ushort_t o0 = f2bf(v.x), o1 = f2bf(v.y), o2 = f2bf(v.z), o3 = f2bf(v.w);
    ((ushort4*)out)[i] = make_ushort4(o0, o1, o2, o3);
}

// C[m,n] = sum_k A[m,k]*B[n,k];  A: M x lda bf16, B: N x ldb bf16.
// 128x128 tile, BK=32, 4 waves, each wave 64x64 (4x4 MFMA 16x16x32 tiles).
// MODE 0: cols<2048 -> outH (xi bf16), cols>=2048 -> outH2 (z bf16)
// MODE 1: bf16 store col<Nact (dbl)
// MODE 2: softplus(acc + biasF[col]) -> outF fp32 (dt)
// MODE 3: fp32 store col<Nact (final output)
template <int MODE>
__global__ __launch_bounds__(256) void gemm_bt(
    const ushort_t* __restrict__ A, int lda,
    const ushort_t* __restrict__ B, int ldb,
    int K, int Nact, int ldc,
    float* __restrict__ outF, ushort_t* __restrict__ outH,
    ushort_t* __restrict__ outH2, const float* __restrict__ biasF)
{
    constexpr int BM = 128, BN = 128, BK = 32;
    __shared__ ushort_t sA[BM * BK];
    __shared__ ushort_t sB[BN * BK];
    const int tid  = threadIdx.x;
    const int m0   = blockIdx.x * BM;
    const int n0   = blockIdx.y * BN;
    const int lane = tid & 63, wave = tid >> 6;
    const int wm   = (wave & 1) * 64, wn = (wave >> 1) * 64;
    const int lm   = lane & 15, quad = lane >> 4;

    floatx4 acc[4][4];
#pragma unroll
    for (int i = 0; i < 4; ++i)
#pragma unroll
        for (int j = 0; j < 4; ++j)
            acc[i][j] = (floatx4){0.f, 0.f, 0.f, 0.f};

    for (int k0 = 0; k0 < K; k0 += BK) {
        __syncthreads();
#pragma unroll
        for (int r = 0; r < 2; ++r) {
            int q   = r * 256 + tid;
            int row = q >> 2;
            int c8  = (q & 3) * 8;
            const ushort_t* gA = A + (size_t)(m0 + row) * lda + (k0 + c8);
            __builtin_amdgcn_global_load_lds((const AS1 void*)gA, (AS3 void*)(&sA[q * 8]), 16, 0, 0);
            int rowB = n0 + row;
            if (rowB >= Nact) rowB = Nact - 1;   // clamp; garbage cols discarded in epilogue
            const ushort_t* gB = B + (size_t)rowB * ldb + (k0 + c8);
            __builtin_amdgcn_global_load_lds((const AS1 void*)gB, (AS3 void*)(&sB[q * 8]), 16, 0, 0);
        }
        __syncthreads();

        short8 af[4], bfr[4];
#pragma unroll
        for (int i = 0; i < 4; ++i)
            af[i] = *(const short8*)&sA[(wm + i * 16 + lm) * BK + quad * 8];
#pragma unroll
        for (int j = 0; j < 4; ++j)
            bfr[j] = *(const short8*)&sB[(wn + j * 16 + lm) * BK + quad * 8];
#pragma unroll
        for (int i = 0; i < 4; ++i)
#pragma unroll
            for (int j = 0; j < 4; ++j)
                acc[i][j] = __builtin_amdgcn_mfma_f32_16x16x32_bf16(af[i], bfr[j], acc[i][j], 0, 0, 0);
    }

#pragma unroll
    for (int i = 0; i < 4; ++i) {
#pragma unroll
        for (int j = 0; j < 4; ++j) {
#pragma unroll
            for (int r = 0; r < 4; ++r) {
                int row = m0 + wm + i * 16 + quad * 4 + r;
                int col = n0 + wn + j * 16 + lm;
                float v = acc[i][j][r];
                if (MODE == 0) {
                    if (col < 2048) outH[(size_t)row * 2048 + col] = f2bf(v);
                    else            outH2[(size_t)row * 2048 + (col - 2048)] = f2bf(v);
                } else if (MODE == 1) {
                    if (col < Nact) outH[(size_t)row * ldc + col] = f2bf(v);
                } else if (MODE == 2) {
                    if (col < Nact) {
                        float x  = v + biasF[col];
                        float sp = (x > 20.f) ? x : log1pf(__expf(x));
                        outF[(size_t)row * ldc + col] = sp;
                    }
                } else {
                    if (col < Nact) outF[(size_t)row * ldc + col] = v;
                }
            }
        }
    }
}

// u = silu(depthwise_causal_conv4(xi) + conv_b), bf16 in/out; weights fp32
__global__ __launch_bounds__(256) void conv_silu_k(
    const ushort_t* __restrict__ xi, const float* __restrict__ conv_w,
    const float* __restrict__ conv_b, ushort_t* __restrict__ u)
{
    int idx = blockIdx.x * 256 + threadIdx.x;     // (b*L + l)*2048 + c
    int c   = idx & 2047;
    int bl  = idx >> 11;
    int l   = bl & 2047;
    float acc = conv_b[c];
#pragma unroll
    for (int k = 0; k < 4; ++k) {
        int ll = l - 3 + k;
        if (ll >= 0)
            acc += bf2f(xi[(size_t)(bl - 3 + k) * 2048 + c]) * conv_w[c * 4 + k];
    }
    float s = acc / (1.f + __expf(-acc));
    u[idx] = f2bf(s);
}

// Selective scan + D-skip + SiLU(z) gating. thread=(channel, state):
// block = 16 channels x 16 states; grid = 4 batches * 128 channel-blocks.
// PF-deep register software pipeline: loop unrolled by PF so slot indices are
// compile-time constants -> slots live in VGPRs; 5 loads/step x PF=8 in flight
// (40 outstanding, under the vmcnt=63 cap). y overwrites z in place (bf16).
__global__ __launch_bounds__(256) void scan_k(
    const float* __restrict__ dt, const ushort_t* __restrict__ u,
    const ushort_t* __restrict__ dbl, ushort_t* zy,
    const float* __restrict__ A_log, const float* __restrict__ D_skip)
{
    constexpr int L  = 2048;
    constexpr int PF = 8;
    const int tid = threadIdx.x;
    const int s   = tid & 15;
    const int cl  = tid >> 4;
    const int b   = blockIdx.x >> 7;
    const int c   = ((blockIdx.x & 127) << 4) + cl;
    const float As  = -__expf(A_log[c * 16 + s]);
    const float Dsk = D_skip[c];
    const size_t baseBL = (size_t)b * L;

    float dtq[PF], uq[PF], Bq[PF], Cq[PF], zq[PF];
#pragma unroll
    for (int j = 0; j < PF; ++j) {
        size_t r = baseBL + j;
        dtq[j] = dt[r * 2048 + c];
        uq[j]  = bf2f(u[r * 2048 + c]);
        Bq[j]  = bf2f(dbl[r * 96 + 64 + s]);
        Cq[j]  = bf2f(dbl[r * 96 + 80 + s]);
        zq[j]  = bf2f(zy[r * 2048 + c]);
    }

    float h = 0.f;
    for (int g = 0; g < L; g += PF) {
#pragma unroll
        for (int j = 0; j < PF; ++j) {
            const int t = g + j;
            float dtv = dtq[j], uv = uq[j], Bv = Bq[j], Cv = Cq[j], zv = zq[j];

            // issue loads for t+PF into slot j (clamped; tail garbage unused)
            int tn = t + PF;
            if (tn >= L) tn = L - 1;
            size_t rn = baseBL + tn;
            dtq[j] = dt[rn * 2048 + c];
            uq[j]  = bf2f(u[rn * 2048 + c]);
            Bq[j]  = bf2f(dbl[rn * 96 + 64 + s]);
            Cq[j]  = bf2f(dbl[rn * 96 + 80 + s]);
            zq[j]  = bf2f(zy[rn * 2048 + c]);

            float dA = __expf(dtv * As);
            h = fmaf(h, dA, dtv * uv * Bv);
            float p = h * Cv;
            p += __shfl_xor(p, 1, 16);
            p += __shfl_xor(p, 2, 16);
            p += __shfl_xor(p, 4, 16);
            p += __shfl_xor(p, 8, 16);
            float g2 = zv / (1.f + __expf(-zv));
            float yv = (p + uv * Dsk) * g2;
            if (s == 0)
                zy[(baseBL + t) * 2048 + c] = f2bf(yv);
        }
    }
}

extern "C" void kernel_launch(void* const* d_in, const int* in_sizes, int n_in,
                              void* d_out, int out_size, void* d_ws, size_t ws_size,
                              hipStream_t stream)
{
    const float* x      = (const float*)d_in[0];   // (4,2048,1024)
    const float* W_in   = (const float*)d_in[1];   // (4096,1024)
    const float* conv_w = (const float*)d_in[2];   // (2048,4)
    const float* conv_b = (const float*)d_in[3];   // (2048,)
    const float* W_xp   = (const float*)d_in[4];   // (96,2048)
    const float* W_dt   = (const float*)d_in[5];   // (2048,64)
    const float* b_dt   = (const float*)d_in[6];   // (2048,)
    const float* A_log  = (const float*)d_in[7];   // (2048,16)
    const float* D_skip = (const float*)d_in[8];   // (2048,)
    const float* W_out  = (const float*)d_in[9];   // (1024,2048)

    char* ws = (char*)d_ws;
    const size_t MB = 1024 * 1024;
    // Region 0 (0..64MB): xi bf16 (32MB) + xw (16MB) + Wib (8MB) during phase 1;
    //                      reused as dt fp32 (64MB) from GEMM4 on (xi/xw/Wib dead).
    ushort_t* xi  = (ushort_t*)(ws);
    ushort_t* xw  = (ushort_t*)(ws + 32 * MB);
    ushort_t* Wib = (ushort_t*)(ws + 48 * MB);
    float*    dt  = (float*)(ws);
    ushort_t* z   = (ushort_t*)(ws + 64 * MB);    // 32MB
    ushort_t* u   = (ushort_t*)(ws + 96 * MB);    // 32MB
    ushort_t* dbl = (ushort_t*)(ws + 128 * MB);   // 1.5MB
    ushort_t* Wxb = (ushort_t*)(ws + 130 * MB);   // 0.375MB
    ushort_t* Wdb = (ushort_t*)(ws + 131 * MB);   // 0.25MB
    ushort_t* Wob = (ushort_t*)(ws + 132 * MB);   // 4MB

    // 0) fp32 -> bf16 casts for GEMM operands
    cast_f2b<<<8192, 256, 0, stream>>>(x, xw, 2097152);       // 8.4M elems
    cast_f2b<<<4096, 256, 0, stream>>>(W_in, Wib, 1048576);   // 4.2M
    cast_f2b<<<192, 256, 0, stream>>>(W_xp, Wxb, 49152);      // 196608
    cast_f2b<<<128, 256, 0, stream>>>(W_dt, Wdb, 32768);      // 131072
    cast_f2b<<<2048, 256, 0, stream>>>(W_out, Wob, 524288);   // 2.1M

    // 1) xz = x @ W_in^T : M=8192, N=4096, K=1024 -> xi bf16 | z bf16
    gemm_bt<0><<<dim3(64, 32), 256, 0, stream>>>(xw, 1024, Wib, 1024, 1024, 4096, 2048,
                                                 nullptr, xi, z, nullptr);
    // 2) u = silu(conv(xi)+b)
    conv_silu_k<<<65536, 256, 0, stream>>>(xi, conv_w, conv_b, u);
    // 3) dbl = u @ W_xproj^T : M=8192, N=96(pad 128), K=2048 -> bf16
    gemm_bt<1><<<dim3(64, 1), 256, 0, stream>>>(u, 2048, Wxb, 2048, 2048, 96, 96,
                                                nullptr, dbl, nullptr, nullptr);
    // 4) dt = softplus(dbl[:, :64] @ W_dt^T + b_dt) : M=8192, N=2048, K=64 -> fp32 (overlays xi)
    gemm_bt<2><<<dim3(64, 16), 256, 0, stream>>>(dbl, 96, Wdb, 64, 64, 2048, 2048,
                                                 dt, nullptr, nullptr, b_dt);
    // 5) selective scan + gating; y overwrites z (bf16)
    scan_k<<<512, 256, 0, stream>>>(dt, u, dbl, z, A_log, D_skip);
    // 6) out = y @ W_out^T : M=8192, N=1024, K=2048 -> fp32 d_out
    gemm_bt<3><<<dim3(64, 8), 256, 0, stream>>>(z, 2048, Wob, 2048, 2048, 1024, 1024,
                                                (float*)d_out, nullptr, nullptr, nullptr);
}

// Round 4
// 603.490 us; speedup vs baseline: 2.0666x; 1.6598x over previous
//
#include <hip/hip_runtime.h>

#define AS1 __attribute__((address_space(1)))
#define AS3 __attribute__((address_space(3)))

typedef unsigned short ushort_t;
typedef __attribute__((ext_vector_type(8))) short short8;
typedef __attribute__((ext_vector_type(4))) float floatx4;

__device__ __forceinline__ float bf2f(ushort_t h) {
    return __uint_as_float(((unsigned int)h) << 16);
}
__device__ __forceinline__ ushort_t f2bf(float f) {
    unsigned int u = __float_as_uint(f);
    u += 0x7fffu + ((u >> 16) & 1u);   // RNE
    return (ushort_t)(u >> 16);
}

// fp32 -> bf16 cast, 4 elems/thread
__global__ __launch_bounds__(256) void cast_f2b(const float* __restrict__ in,
                                                ushort_t* __restrict__ out, int n4)
{
    int i = blockIdx.x * 256 + threadIdx.x;
    if (i >= n4) return;
    float4 v = ((const float4*)in)[i];
    ushort_t o0 = f2bf(v.x), o1 = f2bf(v.y), o2 = f2bf(v.z), o3 = f2bf(v.w);
    ((ushort4*)out)[i] = make_ushort4(o0, o1, o2, o3);
}

// C[m,n] = sum_k A[m,k]*B[n,k];  A: M x lda bf16, B: N x ldb bf16.
// 128x128 tile, BK=32, 4 waves, each wave 64x64 (4x4 MFMA 16x16x32 tiles).
// MODE 0: cols<2048 -> outH (xi bf16), cols>=2048 -> outH2 (z bf16)
// MODE 1: bf16 store col<Nact (dbl); cols 64..95 ALSO stored fp32 to outF (BCf)
// MODE 2: softplus(acc + biasF[col]) -> outF fp32 (dt)
// MODE 3: fp32 store col<Nact (final output)
template <int MODE>
__global__ __launch_bounds__(256) void gemm_bt(
    const ushort_t* __restrict__ A, int lda,
    const ushort_t* __restrict__ B, int ldb,
    int K, int Nact, int ldc,
    float* __restrict__ outF, ushort_t* __restrict__ outH,
    ushort_t* __restrict__ outH2, const float* __restrict__ biasF)
{
    constexpr int BM = 128, BN = 128, BK = 32;
    __shared__ ushort_t sA[BM * BK];
    __shared__ ushort_t sB[BN * BK];
    const int tid  = threadIdx.x;
    const int m0   = blockIdx.x * BM;
    const int n0   = blockIdx.y * BN;
    const int lane = tid & 63, wave = tid >> 6;
    const int wm   = (wave & 1) * 64, wn = (wave >> 1) * 64;
    const int lm   = lane & 15, quad = lane >> 4;

    floatx4 acc[4][4];
#pragma unroll
    for (int i = 0; i < 4; ++i)
#pragma unroll
        for (int j = 0; j < 4; ++j)
            acc[i][j] = (floatx4){0.f, 0.f, 0.f, 0.f};

    for (int k0 = 0; k0 < K; k0 += BK) {
        __syncthreads();
#pragma unroll
        for (int r = 0; r < 2; ++r) {
            int q   = r * 256 + tid;
            int row = q >> 2;
            int c8  = (q & 3) * 8;
            const ushort_t* gA = A + (size_t)(m0 + row) * lda + (k0 + c8);
            __builtin_amdgcn_global_load_lds((const AS1 void*)gA, (AS3 void*)(&sA[q * 8]), 16, 0, 0);
            int rowB = n0 + row;
            if (rowB >= Nact) rowB = Nact - 1;   // clamp; garbage cols discarded in epilogue
            const ushort_t* gB = B + (size_t)rowB * ldb + (k0 + c8);
            __builtin_amdgcn_global_load_lds((const AS1 void*)gB, (AS3 void*)(&sB[q * 8]), 16, 0, 0);
        }
        __syncthreads();

        short8 af[4], bfr[4];
#pragma unroll
        for (int i = 0; i < 4; ++i)
            af[i] = *(const short8*)&sA[(wm + i * 16 + lm) * BK + quad * 8];
#pragma unroll
        for (int j = 0; j < 4; ++j)
            bfr[j] = *(const short8*)&sB[(wn + j * 16 + lm) * BK + quad * 8];
#pragma unroll
        for (int i = 0; i < 4; ++i)
#pragma unroll
            for (int j = 0; j < 4; ++j)
                acc[i][j] = __builtin_amdgcn_mfma_f32_16x16x32_bf16(af[i], bfr[j], acc[i][j], 0, 0, 0);
    }

#pragma unroll
    for (int i = 0; i < 4; ++i) {
#pragma unroll
        for (int j = 0; j < 4; ++j) {
#pragma unroll
            for (int r = 0; r < 4; ++r) {
                int row = m0 + wm + i * 16 + quad * 4 + r;
                int col = n0 + wn + j * 16 + lm;
                float v = acc[i][j][r];
                if (MODE == 0) {
                    if (col < 2048) outH[(size_t)row * 2048 + col] = f2bf(v);
                    else            outH2[(size_t)row * 2048 + (col - 2048)] = f2bf(v);
                } else if (MODE == 1) {
                    if (col < Nact) outH[(size_t)row * ldc + col] = f2bf(v);
                    if (col >= 64 && col < 96) outF[(size_t)row * 32 + (col - 64)] = v;
                } else if (MODE == 2) {
                    if (col < Nact) {
                        float x  = v + biasF[col];
                        float sp = (x > 20.f) ? x : log1pf(__expf(x));
                        outF[(size_t)row * ldc + col] = sp;
                    }
                } else {
                    if (col < Nact) outF[(size_t)row * ldc + col] = v;
                }
            }
        }
    }
}

// u = silu(depthwise_causal_conv4(xi) + conv_b), bf16 in/out; weights fp32
__global__ __launch_bounds__(256) void conv_silu_k(
    const ushort_t* __restrict__ xi, const float* __restrict__ conv_w,
    const float* __restrict__ conv_b, ushort_t* __restrict__ u)
{
    int idx = blockIdx.x * 256 + threadIdx.x;     // (b*L + l)*2048 + c
    int c   = idx & 2047;
    int bl  = idx >> 11;
    int l   = bl & 2047;
    float acc = conv_b[c];
#pragma unroll
    for (int k = 0; k < 4; ++k) {
        int ll = l - 3 + k;
        if (ll >= 0)
            acc += bf2f(xi[(size_t)(bl - 3 + k) * 2048 + c]) * conv_w[c * 4 + k];
    }
    float s = acc / (1.f + __expf(-acc));
    u[idx] = f2bf(s);
}

// ---- chunked 2-pass parallel scan ------------------------------------------
// thread = (b, c, chunk); 16 states in registers; 16 chunks x 128 steps.
// grid: 512 blocks = chunk(16) x b(4) x cblk(8); block = 256 threads over c.
constexpr int CH  = 128;   // steps per chunk
constexpr int NCH = 16;    // chunks
constexpr int NI  = 4 * 2048 * 16;  // (b,c,s) count = 131072

// pass 1: per-chunk carry (P = prod a, S = local scan value from h=0)
__global__ __launch_bounds__(256) void scan_p1(
    const float* __restrict__ dt, const ushort_t* __restrict__ u,
    const float* __restrict__ BC, const float* __restrict__ A_log,
    float* __restrict__ Pbuf, float* __restrict__ Sbuf)
{
    const int tid   = threadIdx.x;
    const int blk   = blockIdx.x;
    const int chunk = blk >> 5;
    const int b     = (blk >> 3) & 3;
    const int c     = ((blk & 7) << 8) + tid;

    float As[16];
#pragma unroll
    for (int s = 0; s < 16; ++s) As[s] = -__expf(A_log[c * 16 + s]);

    float P[16], S[16];
#pragma unroll
    for (int s = 0; s < 16; ++s) { P[s] = 1.f; S[s] = 0.f; }

    const size_t base = (size_t)b * 2048 + chunk * CH;
    for (int t = 0; t < CH; ++t) {
        const size_t r = base + t;
        float dtv = dt[r * 2048 + c];
        float uv  = bf2f(u[r * 2048 + c]);
        float ct  = dtv * uv;
        float Bv[16];
#pragma unroll
        for (int s = 0; s < 16; ++s) Bv[s] = BC[r * 32 + s];
#pragma unroll
        for (int s = 0; s < 16; ++s) {
            float a = __expf(dtv * As[s]);
            P[s] *= a;
            S[s] = fmaf(S[s], a, ct * Bv[s]);
        }
    }
    const size_t o = (size_t)chunk * NI + ((size_t)b * 2048 + c) * 16;
#pragma unroll
    for (int s = 0; s < 16; ++s) { Pbuf[o + s] = P[s]; Sbuf[o + s] = S[s]; }
}

// combine: serial fold of 16 chunk carries per (b,c,s); emits chunk-initial h
__global__ __launch_bounds__(256) void scan_comb(
    const float* __restrict__ Pbuf, const float* __restrict__ Sbuf,
    float* __restrict__ Hbuf)
{
    const int i = blockIdx.x * 256 + threadIdx.x;   // 0..NI-1
    float hi = 0.f;
#pragma unroll
    for (int k = 0; k < NCH; ++k) {
        Hbuf[(size_t)k * NI + i] = hi;
        hi = Sbuf[(size_t)k * NI + i] + Pbuf[(size_t)k * NI + i] * hi;
    }
}

// pass 2: replay chunk from h_init, y = (sum_s h*C + u*D) * silu(z), in-place over z
__global__ __launch_bounds__(256) void scan_p2(
    const float* __restrict__ dt, const ushort_t* __restrict__ u,
    const float* __restrict__ BC, const float* __restrict__ A_log,
    const float* __restrict__ D_skip, const float* __restrict__ Hbuf,
    ushort_t* __restrict__ zy)
{
    const int tid   = threadIdx.x;
    const int blk   = blockIdx.x;
    const int chunk = blk >> 5;
    const int b     = (blk >> 3) & 3;
    const int c     = ((blk & 7) << 8) + tid;

    float As[16], h[16];
#pragma unroll
    for (int s = 0; s < 16; ++s) As[s] = -__expf(A_log[c * 16 + s]);
    const float Dsk = D_skip[c];
    const size_t o = (size_t)chunk * NI + ((size_t)b * 2048 + c) * 16;
#pragma unroll
    for (int s = 0; s < 16; ++s) h[s] = Hbuf[o + s];

    const size_t base = (size_t)b * 2048 + chunk * CH;
    for (int t = 0; t < CH; ++t) {
        const size_t r = base + t;
        float dtv = dt[r * 2048 + c];
        float uv  = bf2f(u[r * 2048 + c]);
        float zv  = bf2f(zy[r * 2048 + c]);
        float ct  = dtv * uv;
        float Bv[16], Cv[16];
#pragma unroll
        for (int s = 0; s < 16; ++s) Bv[s] = BC[r * 32 + s];
#pragma unroll
        for (int s = 0; s < 16; ++s) Cv[s] = BC[r * 32 + 16 + s];
        float p0 = 0.f, p1 = 0.f, p2 = 0.f, p3 = 0.f;
#pragma unroll
        for (int s = 0; s < 16; s += 4) {
            float a0 = __expf(dtv * As[s]);
            float a1 = __expf(dtv * As[s + 1]);
            float a2 = __expf(dtv * As[s + 2]);
            float a3 = __expf(dtv * As[s + 3]);
            h[s]     = fmaf(h[s],     a0, ct * Bv[s]);
            h[s + 1] = fmaf(h[s + 1], a1, ct * Bv[s + 1]);
            h[s + 2] = fmaf(h[s + 2], a2, ct * Bv[s + 2]);
            h[s + 3] = fmaf(h[s + 3], a3, ct * Bv[s + 3]);
            p0 = fmaf(h[s],     Cv[s],     p0);
            p1 = fmaf(h[s + 1], Cv[s + 1], p1);
            p2 = fmaf(h[s + 2], Cv[s + 2], p2);
            p3 = fmaf(h[s + 3], Cv[s + 3], p3);
        }
        float p = (p0 + p1) + (p2 + p3);
        float g = zv / (1.f + __expf(-zv));
        float yv = (p + uv * Dsk) * g;
        zy[r * 2048 + c] = f2bf(yv);
    }
}

extern "C" void kernel_launch(void* const* d_in, const int* in_sizes, int n_in,
                              void* d_out, int out_size, void* d_ws, size_t ws_size,
                              hipStream_t stream)
{
    const float* x      = (const float*)d_in[0];   // (4,2048,1024)
    const float* W_in   = (const float*)d_in[1];   // (4096,1024)
    const float* conv_w = (const float*)d_in[2];   // (2048,4)
    const float* conv_b = (const float*)d_in[3];   // (2048,)
    const float* W_xp   = (const float*)d_in[4];   // (96,2048)
    const float* W_dt   = (const float*)d_in[5];   // (2048,64)
    const float* b_dt   = (const float*)d_in[6];   // (2048,)
    const float* A_log  = (const float*)d_in[7];   // (2048,16)
    const float* D_skip = (const float*)d_in[8];   // (2048,)
    const float* W_out  = (const float*)d_in[9];   // (1024,2048)

    char* ws = (char*)d_ws;
    const size_t MB = 1024 * 1024;
    // 0..64MB: xi(0..32) + xw(32..48) + Wib(48..56) in phase 1; dt fp32 after GEMM4.
    ushort_t* xi  = (ushort_t*)(ws);
    ushort_t* xw  = (ushort_t*)(ws + 32 * MB);
    ushort_t* Wib = (ushort_t*)(ws + 48 * MB);
    float*    dt  = (float*)(ws);
    ushort_t* z   = (ushort_t*)(ws + 64 * MB);    // 32MB
    ushort_t* u   = (ushort_t*)(ws + 96 * MB);    // 32MB
    ushort_t* dbl = (ushort_t*)(ws + 128 * MB);   // 1.5MB
    ushort_t* Wxb = (ushort_t*)(ws + 130 * MB);   // 0.375MB
    ushort_t* Wdb = (ushort_t*)(ws + 131 * MB);   // 0.25MB
    ushort_t* Wob = (ushort_t*)(ws + 132 * MB);   // 4MB
    float*    BCf = (float*)(ws + 137 * MB);      // 1MB  (8192 x 32 fp32: B|C)
    float*    Pb  = (float*)(ws + 138 * MB);      // 8MB
    float*    Sb  = (float*)(ws + 146 * MB);      // 8MB
    float*    Hb  = (float*)(ws + 154 * MB);      // 8MB

    // 0) fp32 -> bf16 casts for GEMM operands
    cast_f2b<<<8192, 256, 0, stream>>>(x, xw, 2097152);
    cast_f2b<<<4096, 256, 0, stream>>>(W_in, Wib, 1048576);
    cast_f2b<<<192, 256, 0, stream>>>(W_xp, Wxb, 49152);
    cast_f2b<<<128, 256, 0, stream>>>(W_dt, Wdb, 32768);
    cast_f2b<<<2048, 256, 0, stream>>>(W_out, Wob, 524288);

    // 1) xz = x @ W_in^T : M=8192, N=4096, K=1024 -> xi bf16 | z bf16
    gemm_bt<0><<<dim3(64, 32), 256, 0, stream>>>(xw, 1024, Wib, 1024, 1024, 4096, 2048,
                                                 nullptr, xi, z, nullptr);
    // 2) u = silu(conv(xi)+b)
    conv_silu_k<<<65536, 256, 0, stream>>>(xi, conv_w, conv_b, u);
    // 3) dbl = u @ W_xproj^T (bf16) + B/C cols as fp32 BCf
    gemm_bt<1><<<dim3(64, 1), 256, 0, stream>>>(u, 2048, Wxb, 2048, 2048, 96, 96,
                                                BCf, dbl, nullptr, nullptr);
    // 4) dt = softplus(dbl[:, :64] @ W_dt^T + b_dt) -> fp32 (overlays xi)
    gemm_bt<2><<<dim3(64, 16), 256, 0, stream>>>(dbl, 96, Wdb, 64, 64, 2048, 2048,
                                                 dt, nullptr, nullptr, b_dt);
    // 5) chunked parallel scan + gating; y overwrites z (bf16)
    scan_p1<<<512, 256, 0, stream>>>(dt, u, BCf, A_log, Pb, Sb);
    scan_comb<<<512, 256, 0, stream>>>(Pb, Sb, Hb);
    scan_p2<<<512, 256, 0, stream>>>(dt, u, BCf, A_log, D_skip, Hb, z);
    // 6) out = y @ W_out^T : M=8192, N=1024, K=2048 -> fp32 d_out
    gemm_bt<3><<<dim3(64, 8), 256, 0, stream>>>(z, 2048, Wob, 2048, 2048, 1024, 1024,
                                                (float*)d_out, nullptr, nullptr, nullptr);
}

// Round 5
// 551.898 us; speedup vs baseline: 2.2597x; 1.0935x over previous
//
#include <hip/hip_runtime.h>

#define AS1 __attribute__((address_space(1)))
#define AS3 __attribute__((address_space(3)))

typedef unsigned short ushort_t;
typedef __attribute__((ext_vector_type(8))) short short8;
typedef __attribute__((ext_vector_type(4))) float floatx4;

__device__ __forceinline__ float bf2f(ushort_t h) {
    return __uint_as_float(((unsigned int)h) << 16);
}
__device__ __forceinline__ ushort_t f2bf(float f) {
    unsigned int u = __float_as_uint(f);
    u += 0x7fffu + ((u >> 16) & 1u);   // RNE
    return (ushort_t)(u >> 16);
}

// single merged fp32 -> bf16 cast over 5 arrays (float4 granularity)
__global__ __launch_bounds__(256) void cast_all(
    const float* __restrict__ s0, ushort_t* __restrict__ d0,   // x      2097152 f4
    const float* __restrict__ s1, ushort_t* __restrict__ d1,   // W_in   1048576
    const float* __restrict__ s2, ushort_t* __restrict__ d2,   // W_xp     49152
    const float* __restrict__ s3, ushort_t* __restrict__ d3,   // W_dt     32768
    const float* __restrict__ s4, ushort_t* __restrict__ d4)   // W_out   524288
{
    int i = blockIdx.x * 256 + threadIdx.x;
    const float* src; ushort_t* dst; int off;
    if      (i < 2097152) { src = s0; dst = d0; off = i; }
    else if (i < 3145728) { src = s1; dst = d1; off = i - 2097152; }
    else if (i < 3194880) { src = s2; dst = d2; off = i - 3145728; }
    else if (i < 3227648) { src = s3; dst = d3; off = i - 3194880; }
    else                  { src = s4; dst = d4; off = i - 3227648; }
    float4 v = ((const float4*)src)[off];
    ((ushort4*)dst)[off] = make_ushort4(f2bf(v.x), f2bf(v.y), f2bf(v.z), f2bf(v.w));
}

// C[m,n] = sum_k A[m,k]*B[n,k];  A: M x lda bf16, B: N x ldb bf16.
// 128x128 tile, BK=64, XOR-swizzled LDS (granule hh = (g&7)^(row&7)) ->
// ds_read_b128 is 2-way-conflict max (free). 4 waves, wave = 64x64.
// MODE 0: cols<2048 -> outH (xi bf16), cols>=2048 -> outH2 (z bf16)
// MODE 1: bf16 store col<Nact (dbl); cols 64..95 ALSO stored fp32 to outF (BCf)
// MODE 2: softplus(acc + biasF[col]) -> fp16 (bits in outH)
// MODE 3: fp32 store col<Nact (final output)
template <int MODE>
__global__ __launch_bounds__(256) void gemm_bt(
    const ushort_t* __restrict__ A, int lda,
    const ushort_t* __restrict__ B, int ldb,
    int K, int Nact, int ldc,
    float* __restrict__ outF, ushort_t* __restrict__ outH,
    ushort_t* __restrict__ outH2, const float* __restrict__ biasF)
{
    constexpr int BM = 128, BN = 128, BK = 64;
    __shared__ ushort_t sA[BM * BK];   // 16 KB, granule(16B)-swizzled
    __shared__ ushort_t sB[BN * BK];
    const int tid  = threadIdx.x;
    const int m0   = blockIdx.x * BM;
    const int n0   = blockIdx.y * BN;
    const int lane = tid & 63, wave = tid >> 6;
    const int wm   = (wave & 1) * 64, wn = (wave >> 1) * 64;
    const int lm   = lane & 15, quad = lane >> 4;
    const int lm7  = lane & 7;

    floatx4 acc[4][4];
#pragma unroll
    for (int i = 0; i < 4; ++i)
#pragma unroll
        for (int j = 0; j < 4; ++j)
            acc[i][j] = (floatx4){0.f, 0.f, 0.f, 0.f};

    for (int k0 = 0; k0 < K; k0 += BK) {
        __syncthreads();
#pragma unroll
        for (int r = 0; r < 4; ++r) {
            int g   = r * 256 + tid;            // granule index 0..1023
            int row = g >> 3;
            int hh  = (g & 7) ^ (row & 7);      // swizzled 16B-granule in row
            int col = k0 + hh * 8;
            const ushort_t* gA = A + (size_t)(m0 + row) * lda + col;
            __builtin_amdgcn_global_load_lds((const AS1 void*)gA, (AS3 void*)(&sA[g * 8]), 16, 0, 0);
            int rowB = n0 + row;
            if (rowB >= Nact) rowB = Nact - 1;  // clamp; garbage cols discarded in epilogue
            const ushort_t* gB = B + (size_t)rowB * ldb + col;
            __builtin_amdgcn_global_load_lds((const AS1 void*)gB, (AS3 void*)(&sB[g * 8]), 16, 0, 0);
        }
        __syncthreads();

#pragma unroll
        for (int s = 0; s < 2; ++s) {
            short8 af[4], bfr[4];
#pragma unroll
            for (int i = 0; i < 4; ++i) {
                int row = wm + i * 16 + lm;
                int gr  = row * 8 + ((s * 4 + quad) ^ lm7);
                af[i] = *(const short8*)&sA[gr * 8];
            }
#pragma unroll
            for (int j = 0; j < 4; ++j) {
                int row = wn + j * 16 + lm;
                int gr  = row * 8 + ((s * 4 + quad) ^ lm7);
                bfr[j] = *(const short8*)&sB[gr * 8];
            }
#pragma unroll
            for (int i = 0; i < 4; ++i)
#pragma unroll
                for (int j = 0; j < 4; ++j)
                    acc[i][j] = __builtin_amdgcn_mfma_f32_16x16x32_bf16(af[i], bfr[j], acc[i][j], 0, 0, 0);
        }
    }

#pragma unroll
    for (int i = 0; i < 4; ++i) {
#pragma unroll
        for (int j = 0; j < 4; ++j) {
#pragma unroll
            for (int r = 0; r < 4; ++r) {
                int row = m0 + wm + i * 16 + quad * 4 + r;
                int col = n0 + wn + j * 16 + lm;
                float v = acc[i][j][r];
                if (MODE == 0) {
                    if (col < 2048) outH[(size_t)row * 2048 + col] = f2bf(v);
                    else            outH2[(size_t)row * 2048 + (col - 2048)] = f2bf(v);
                } else if (MODE == 1) {
                    if (col < Nact) outH[(size_t)row * ldc + col] = f2bf(v);
                    if (col >= 64 && col < 96) outF[(size_t)row * 32 + (col - 64)] = v;
                } else if (MODE == 2) {
                    float x  = v + biasF[col];
                    float sp = (x > 20.f) ? x : log1pf(__expf(x));
                    _Float16 hv = (_Float16)sp;
                    outH[(size_t)row * ldc + col] = *(ushort_t*)&hv;
                } else {
                    if (col < Nact) outF[(size_t)row * ldc + col] = v;
                }
            }
        }
    }
}

// u = silu(depthwise_causal_conv4(xi) + conv_b), bf16 in/out; weights fp32
__global__ __launch_bounds__(256) void conv_silu_k(
    const ushort_t* __restrict__ xi, const float* __restrict__ conv_w,
    const float* __restrict__ conv_b, ushort_t* __restrict__ u)
{
    int idx = blockIdx.x * 256 + threadIdx.x;     // (b*L + l)*2048 + c
    int c   = idx & 2047;
    int bl  = idx >> 11;
    int l   = bl & 2047;
    float acc = conv_b[c];
#pragma unroll
    for (int k = 0; k < 4; ++k) {
        int ll = l - 3 + k;
        if (ll >= 0)
            acc += bf2f(xi[(size_t)(bl - 3 + k) * 2048 + c]) * conv_w[c * 4 + k];
    }
    float s = acc / (1.f + __expf(-acc));
    u[idx] = f2bf(s);
}

// ---- chunked 2-pass parallel scan ------------------------------------------
// thread = (b, c, chunk); 16 states in registers; 32 chunks x 64 steps.
// grid: 1024 blocks = chunk(32) x b(4) x cblk(8); block = 256 threads over c.
// carry layout: [chunk][s][b*2048+c] -> fully coalesced
constexpr int CH  = 64;
constexpr int NCH = 32;
constexpr int NI  = 4 * 2048 * 16;  // 131072

__global__ __launch_bounds__(256) void scan_p1(
    const _Float16* __restrict__ dt, const ushort_t* __restrict__ u,
    const float* __restrict__ BC, const float* __restrict__ A_log,
    float* __restrict__ Pbuf, float* __restrict__ Sbuf)
{
    const int tid   = threadIdx.x;
    const int blk   = blockIdx.x;
    const int chunk = blk >> 5;
    const int b     = (blk >> 3) & 3;
    const int c     = ((blk & 7) << 8) + tid;

    float As[16];
#pragma unroll
    for (int s = 0; s < 16; ++s) As[s] = -__expf(A_log[c * 16 + s]);

    float P[16], S[16];
#pragma unroll
    for (int s = 0; s < 16; ++s) { P[s] = 1.f; S[s] = 0.f; }

    const size_t base = (size_t)b * 2048 + chunk * CH;
    for (int t = 0; t < CH; ++t) {
        const size_t r = base + t;
        float dtv = (float)dt[r * 2048 + c];
        float uv  = bf2f(u[r * 2048 + c]);
        float ct  = dtv * uv;
        float Bv[16];
#pragma unroll
        for (int s = 0; s < 16; ++s) Bv[s] = BC[r * 32 + s];
#pragma unroll
        for (int s = 0; s < 16; ++s) {
            float a = __expf(dtv * As[s]);
            P[s] *= a;
            S[s] = fmaf(S[s], a, ct * Bv[s]);
        }
    }
    const size_t ob = (size_t)chunk * NI + (size_t)b * 2048 + c;
#pragma unroll
    for (int s = 0; s < 16; ++s) {
        Pbuf[ob + (size_t)s * 8192] = P[s];
        Sbuf[ob + (size_t)s * 8192] = S[s];
    }
}

// serial fold of 32 chunk carries per (b,c,s); emits chunk-initial h
__global__ __launch_bounds__(256) void scan_comb(
    const float* __restrict__ Pbuf, const float* __restrict__ Sbuf,
    float* __restrict__ Hbuf)
{
    const int i = blockIdx.x * 256 + threadIdx.x;   // 0..NI-1 (= s*8192 + bc)
    float hi = 0.f;
#pragma unroll
    for (int k = 0; k < NCH; ++k) {
        Hbuf[(size_t)k * NI + i] = hi;
        hi = Sbuf[(size_t)k * NI + i] + Pbuf[(size_t)k * NI + i] * hi;
    }
}

// pass 2: replay chunk from h_init, y = (sum_s h*C + u*D) * silu(z), in-place over z
__global__ __launch_bounds__(256) void scan_p2(
    const _Float16* __restrict__ dt, const ushort_t* __restrict__ u,
    const float* __restrict__ BC, const float* __restrict__ A_log,
    const float* __restrict__ D_skip, const float* __restrict__ Hbuf,
    ushort_t* __restrict__ zy)
{
    const int tid   = threadIdx.x;
    const int blk   = blockIdx.x;
    const int chunk = blk >> 5;
    const int b     = (blk >> 3) & 3;
    const int c     = ((blk & 7) << 8) + tid;

    float As[16], h[16];
#pragma unroll
    for (int s = 0; s < 16; ++s) As[s] = -__expf(A_log[c * 16 + s]);
    const float Dsk = D_skip[c];
    const size_t ob = (size_t)chunk * NI + (size_t)b * 2048 + c;
#pragma unroll
    for (int s = 0; s < 16; ++s) h[s] = Hbuf[ob + (size_t)s * 8192];

    const size_t base = (size_t)b * 2048 + chunk * CH;
    for (int t = 0; t < CH; ++t) {
        const size_t r = base + t;
        float dtv = (float)dt[r * 2048 + c];
        float uv  = bf2f(u[r * 2048 + c]);
        float zv  = bf2f(zy[r * 2048 + c]);
        float ct  = dtv * uv;
        float Bv[16], Cv[16];
#pragma unroll
        for (int s = 0; s < 16; ++s) Bv[s] = BC[r * 32 + s];
#pragma unroll
        for (int s = 0; s < 16; ++s) Cv[s] = BC[r * 32 + 16 + s];
        float p0 = 0.f, p1 = 0.f, p2 = 0.f, p3 = 0.f;
#pragma unroll
        for (int s = 0; s < 16; s += 4) {
            float a0 = __expf(dtv * As[s]);
            float a1 = __expf(dtv * As[s + 1]);
            float a2 = __expf(dtv * As[s + 2]);
            float a3 = __expf(dtv * As[s + 3]);
            h[s]     = fmaf(h[s],     a0, ct * Bv[s]);
            h[s + 1] = fmaf(h[s + 1], a1, ct * Bv[s + 1]);
            h[s + 2] = fmaf(h[s + 2], a2, ct * Bv[s + 2]);
            h[s + 3] = fmaf(h[s + 3], a3, ct * Bv[s + 3]);
            p0 = fmaf(h[s],     Cv[s],     p0);
            p1 = fmaf(h[s + 1], Cv[s + 1], p1);
            p2 = fmaf(h[s + 2], Cv[s + 2], p2);
            p3 = fmaf(h[s + 3], Cv[s + 3], p3);
        }
        float p = (p0 + p1) + (p2 + p3);
        float g = zv / (1.f + __expf(-zv));
        float yv = (p + uv * Dsk) * g;
        zy[r * 2048 + c] = f2bf(yv);
    }
}

extern "C" void kernel_launch(void* const* d_in, const int* in_sizes, int n_in,
                              void* d_out, int out_size, void* d_ws, size_t ws_size,
                              hipStream_t stream)
{
    const float* x      = (const float*)d_in[0];   // (4,2048,1024)
    const float* W_in   = (const float*)d_in[1];   // (4096,1024)
    const float* conv_w = (const float*)d_in[2];   // (2048,4)
    const float* conv_b = (const float*)d_in[3];   // (2048,)
    const float* W_xp   = (const float*)d_in[4];   // (96,2048)
    const float* W_dt   = (const float*)d_in[5];   // (2048,64)
    const float* b_dt   = (const float*)d_in[6];   // (2048,)
    const float* A_log  = (const float*)d_in[7];   // (2048,16)
    const float* D_skip = (const float*)d_in[8];   // (2048,)
    const float* W_out  = (const float*)d_in[9];   // (1024,2048)

    char* ws = (char*)d_ws;
    const size_t MB = 1024 * 1024;
    // phase 1: xi 0-32, xw 32-48, Wib 48-56
    // after conv/GEMM0: dt(fp16) 0-32, Pb 32-48, Sb 48-64
    ushort_t*  xi  = (ushort_t*)(ws);
    ushort_t*  xw  = (ushort_t*)(ws + 32 * MB);
    ushort_t*  Wib = (ushort_t*)(ws + 48 * MB);
    _Float16*  dt  = (_Float16*)(ws);
    float*     Pb  = (float*)(ws + 32 * MB);
    float*     Sb  = (float*)(ws + 48 * MB);
    ushort_t*  z   = (ushort_t*)(ws + 64 * MB);    // 32MB
    ushort_t*  u   = (ushort_t*)(ws + 96 * MB);    // 32MB
    ushort_t*  dbl = (ushort_t*)(ws + 128 * MB);   // 1.5MB
    ushort_t*  Wxb = (ushort_t*)(ws + 130 * MB);
    ushort_t*  Wdb = (ushort_t*)(ws + 131 * MB);
    ushort_t*  Wob = (ushort_t*)(ws + 132 * MB);   // 4MB
    float*     BCf = (float*)(ws + 137 * MB);      // 1MB
    float*     Hb  = (float*)(ws + 138 * MB);      // 16MB -> ends 154MB

    // 0) all fp32 -> bf16 casts in one kernel (3751936 float4s)
    cast_all<<<14656, 256, 0, stream>>>(x, xw, W_in, Wib, W_xp, Wxb, W_dt, Wdb, W_out, Wob);

    // 1) xz = x @ W_in^T : M=8192, N=4096, K=1024 -> xi bf16 | z bf16
    gemm_bt<0><<<dim3(64, 32), 256, 0, stream>>>(xw, 1024, Wib, 1024, 1024, 4096, 2048,
                                                 nullptr, xi, z, nullptr);
    // 2) u = silu(conv(xi)+b)
    conv_silu_k<<<65536, 256, 0, stream>>>(xi, conv_w, conv_b, u);
    // 3) dbl = u @ W_xproj^T (bf16) + B/C cols fp32 -> BCf
    gemm_bt<1><<<dim3(64, 1), 256, 0, stream>>>(u, 2048, Wxb, 2048, 2048, 96, 96,
                                                BCf, dbl, nullptr, nullptr);
    // 4) dt = softplus(dbl[:, :64] @ W_dt^T + b_dt) -> fp16 (overlays xi)
    gemm_bt<2><<<dim3(64, 16), 256, 0, stream>>>(dbl, 96, Wdb, 64, 64, 2048, 2048,
                                                 nullptr, (ushort_t*)dt, nullptr, b_dt);
    // 5) chunked parallel scan + gating; y overwrites z (bf16)
    scan_p1<<<1024, 256, 0, stream>>>(dt, u, BCf, A_log, Pb, Sb);
    scan_comb<<<512, 256, 0, stream>>>(Pb, Sb, Hb);
    scan_p2<<<1024, 256, 0, stream>>>(dt, u, BCf, A_log, D_skip, Hb, z);
    // 6) out = y @ W_out^T : M=8192, N=1024, K=2048 -> fp32 d_out
    gemm_bt<3><<<dim3(64, 8), 256, 0, stream>>>(z, 2048, Wob, 2048, 2048, 1024, 1024,
                                                (float*)d_out, nullptr, nullptr, nullptr);
}

// Round 6
// 530.754 us; speedup vs baseline: 2.3498x; 1.0398x over previous
//
#include <hip/hip_runtime.h>

#define AS1 __attribute__((address_space(1)))
#define AS3 __attribute__((address_space(3)))

typedef unsigned short ushort_t;
typedef __attribute__((ext_vector_type(8))) short short8;
typedef __attribute__((ext_vector_type(4))) float floatx4;

__device__ __forceinline__ float bf2f(ushort_t h) {
    return __uint_as_float(((unsigned int)h) << 16);
}
__device__ __forceinline__ ushort_t f2bf(float f) {
    unsigned int u = __float_as_uint(f);
    u += 0x7fffu + ((u >> 16) & 1u);   // RNE
    return (ushort_t)(u >> 16);
}

// single merged fp32 -> bf16 cast over 5 arrays (float4 granularity)
__global__ __launch_bounds__(256) void cast_all(
    const float* __restrict__ s0, ushort_t* __restrict__ d0,   // x      2097152 f4
    const float* __restrict__ s1, ushort_t* __restrict__ d1,   // W_in   1048576
    const float* __restrict__ s2, ushort_t* __restrict__ d2,   // W_xp     49152
    const float* __restrict__ s3, ushort_t* __restrict__ d3,   // W_dt     32768
    const float* __restrict__ s4, ushort_t* __restrict__ d4)   // W_out   524288
{
    int i = blockIdx.x * 256 + threadIdx.x;
    const float* src; ushort_t* dst; int off;
    if      (i < 2097152) { src = s0; dst = d0; off = i; }
    else if (i < 3145728) { src = s1; dst = d1; off = i - 2097152; }
    else if (i < 3194880) { src = s2; dst = d2; off = i - 3145728; }
    else if (i < 3227648) { src = s3; dst = d3; off = i - 3194880; }
    else                  { src = s4; dst = d4; off = i - 3227648; }
    float4 v = ((const float4*)src)[off];
    ((ushort4*)dst)[off] = make_ushort4(f2bf(v.x), f2bf(v.y), f2bf(v.z), f2bf(v.w));
}

// C[m,n] = sum_k A[m,k]*B[n,k];  A: M x lda bf16, B: N x ldb bf16.
// 128x128 tile, BK=64, XOR-swizzled LDS (granule hh = (g&7)^(row&7)) ->
// ds_read_b128 is 2-way-conflict max (free). 4 waves, wave = 64x64.
// MODE 0: cols<2048 -> outH (xi bf16), cols>=2048 -> outH2 (z bf16)
// MODE 2: softplus(acc + biasF[col]) -> fp16 (bits in outH)
// MODE 3: fp32 store col<Nact (final output)
// MODE 4: split-K partial (seg = blockIdx.y, n0 = 0): fp32 partial col<96
template <int MODE>
__global__ __launch_bounds__(256) void gemm_bt(
    const ushort_t* __restrict__ A, int lda,
    const ushort_t* __restrict__ B, int ldb,
    int K, int Nact, int ldc,
    float* __restrict__ outF, ushort_t* __restrict__ outH,
    ushort_t* __restrict__ outH2, const float* __restrict__ biasF)
{
    constexpr int BM = 128, BN = 128, BK = 64;
    __shared__ ushort_t sA[BM * BK];   // 16 KB, granule(16B)-swizzled
    __shared__ ushort_t sB[BN * BK];
    const int tid  = threadIdx.x;
    const int m0   = blockIdx.x * BM;
    const int seg  = (MODE == 4) ? blockIdx.y : 0;
    const int n0   = (MODE == 4) ? 0 : blockIdx.y * BN;
    if (MODE == 4) { A += seg * 512; B += seg * 512; }
    const int lane = tid & 63, wave = tid >> 6;
    const int wm   = (wave & 1) * 64, wn = (wave >> 1) * 64;
    const int lm   = lane & 15, quad = lane >> 4;
    const int lm7  = lane & 7;

    floatx4 acc[4][4];
#pragma unroll
    for (int i = 0; i < 4; ++i)
#pragma unroll
        for (int j = 0; j < 4; ++j)
            acc[i][j] = (floatx4){0.f, 0.f, 0.f, 0.f};

    for (int k0 = 0; k0 < K; k0 += BK) {
        __syncthreads();
#pragma unroll
        for (int r = 0; r < 4; ++r) {
            int g   = r * 256 + tid;            // granule index 0..1023
            int row = g >> 3;
            int hh  = (g & 7) ^ (row & 7);      // swizzled 16B-granule in row
            int col = k0 + hh * 8;
            const ushort_t* gA = A + (size_t)(m0 + row) * lda + col;
            __builtin_amdgcn_global_load_lds((const AS1 void*)gA, (AS3 void*)(&sA[g * 8]), 16, 0, 0);
            int rowB = n0 + row;
            if (rowB >= Nact) rowB = Nact - 1;  // clamp; garbage cols discarded in epilogue
            const ushort_t* gB = B + (size_t)rowB * ldb + col;
            __builtin_amdgcn_global_load_lds((const AS1 void*)gB, (AS3 void*)(&sB[g * 8]), 16, 0, 0);
        }
        __syncthreads();

#pragma unroll
        for (int s = 0; s < 2; ++s) {
            short8 af[4], bfr[4];
#pragma unroll
            for (int i = 0; i < 4; ++i) {
                int row = wm + i * 16 + lm;
                int gr  = row * 8 + ((s * 4 + quad) ^ lm7);
                af[i] = *(const short8*)&sA[gr * 8];
            }
#pragma unroll
            for (int j = 0; j < 4; ++j) {
                int row = wn + j * 16 + lm;
                int gr  = row * 8 + ((s * 4 + quad) ^ lm7);
                bfr[j] = *(const short8*)&sB[gr * 8];
            }
#pragma unroll
            for (int i = 0; i < 4; ++i)
#pragma unroll
                for (int j = 0; j < 4; ++j)
                    acc[i][j] = __builtin_amdgcn_mfma_f32_16x16x32_bf16(af[i], bfr[j], acc[i][j], 0, 0, 0);
        }
    }

#pragma unroll
    for (int i = 0; i < 4; ++i) {
#pragma unroll
        for (int j = 0; j < 4; ++j) {
#pragma unroll
            for (int r = 0; r < 4; ++r) {
                int row = m0 + wm + i * 16 + quad * 4 + r;
                int col = n0 + wn + j * 16 + lm;
                float v = acc[i][j][r];
                if (MODE == 0) {
                    if (col < 2048) outH[(size_t)row * 2048 + col] = f2bf(v);
                    else            outH2[(size_t)row * 2048 + (col - 2048)] = f2bf(v);
                } else if (MODE == 2) {
                    float x  = v + biasF[col];
                    float sp = (x > 20.f) ? x : log1pf(__expf(x));
                    _Float16 hv = (_Float16)sp;
                    outH[(size_t)row * ldc + col] = *(ushort_t*)&hv;
                } else if (MODE == 3) {
                    if (col < Nact) outF[(size_t)row * ldc + col] = v;
                } else if (MODE == 4) {
                    if (col < 96)
                        outF[(size_t)seg * 786432 + (size_t)row * 96 + col] = v;
                }
            }
        }
    }
}

// combine split-K partials: dbl bf16 (8192x96) + B/C cols fp32 -> BCf (8192x32)
__global__ __launch_bounds__(256) void comb3(
    const float* __restrict__ Pg, ushort_t* __restrict__ dbl,
    float* __restrict__ BCf)
{
    int i = blockIdx.x * 256 + threadIdx.x;   // 0..786431
    float v = Pg[i] + Pg[i + 786432] + Pg[i + 2 * 786432] + Pg[i + 3 * 786432];
    dbl[i] = f2bf(v);
    int col = i % 96;
    if (col >= 64) BCf[(size_t)(i / 96) * 32 + (col - 64)] = v;
}

// u = silu(depthwise_causal_conv4(xi) + conv_b); 4 outputs along l per thread
__global__ __launch_bounds__(256) void conv_silu_k(
    const ushort_t* __restrict__ xi, const float* __restrict__ conv_w,
    const float* __restrict__ conv_b, ushort_t* __restrict__ u)
{
    int idx = blockIdx.x * 256 + threadIdx.x;  // 0..4194303
    int c   = idx & 2047;
    int lg  = idx >> 11;        // 0..2047
    int b   = lg >> 9;
    int l0  = (lg & 511) * 4;
    const size_t base = ((size_t)b * 2048 + l0) * 2048 + c;

    float w0 = conv_w[c * 4], w1 = conv_w[c * 4 + 1],
          w2 = conv_w[c * 4 + 2], w3 = conv_w[c * 4 + 3];
    float bias = conv_b[c];

    float xv[7];
#pragma unroll
    for (int j = 0; j < 3; ++j)
        xv[j] = (l0 - 3 + j >= 0) ? bf2f(xi[base + (j - 3) * 2048]) : 0.f;
#pragma unroll
    for (int j = 3; j < 7; ++j)
        xv[j] = bf2f(xi[base + (j - 3) * 2048]);

#pragma unroll
    for (int i = 0; i < 4; ++i) {
        float acc = bias + w0 * xv[i] + w1 * xv[i + 1] + w2 * xv[i + 2] + w3 * xv[i + 3];
        float s = acc / (1.f + __expf(-acc));
        u[base + i * 2048] = f2bf(s);
    }
}

// ---- chunked 2-pass parallel scan ------------------------------------------
// thread = (b, c, chunk); 16 states in registers; 32 chunks x 64 steps.
// grid: 1024 blocks = chunk(32) x b(4) x cblk(8); block = 256 threads over c.
// B/C staged in LDS per block (wave-uniform broadcast reads).
// carry layout: [chunk][s][b*2048+c] -> fully coalesced
constexpr int CH  = 64;
constexpr int NCH = 32;
constexpr int NI  = 4 * 2048 * 16;  // 131072

__global__ __launch_bounds__(256) void scan_p1(
    const _Float16* __restrict__ dt, const ushort_t* __restrict__ u,
    const float* __restrict__ BC, const float* __restrict__ A_log,
    float* __restrict__ Pbuf, float* __restrict__ Sbuf)
{
    __shared__ float sBC[CH * 32];
    const int tid   = threadIdx.x;
    const int blk   = blockIdx.x;
    const int chunk = blk >> 5;
    const int b     = (blk >> 3) & 3;
    const int c     = ((blk & 7) << 8) + tid;
    const size_t base = (size_t)b * 2048 + chunk * CH;

    // stage this chunk's B/C rows (64 x 32 floats = 8KB)
    {
        const float4* src = (const float4*)(BC + base * 32);
        float4* dst = (float4*)sBC;
        dst[tid]       = src[tid];
        dst[tid + 256] = src[tid + 256];
    }
    // As2 = -exp(A_log) * log2(e)  (prescaled for exp2)
    float As2[16];
#pragma unroll
    for (int s = 0; s < 16; ++s) As2[s] = -__expf(A_log[c * 16 + s]) * 1.44269504f;
    __syncthreads();

    float S[16];
#pragma unroll
    for (int s = 0; s < 16; ++s) S[s] = 0.f;
    float cumdt = 0.f;

    for (int t = 0; t < CH; ++t) {
        const size_t r = base + t;
        float dtv = (float)dt[r * 2048 + c];
        float uv  = bf2f(u[r * 2048 + c]);
        float ct  = dtv * uv;
        cumdt += dtv;
#pragma unroll
        for (int s = 0; s < 16; ++s) {
            float a = exp2f(dtv * As2[s]);
            S[s] = fmaf(S[s], a, ct * sBC[t * 32 + s]);
        }
    }
    const size_t ob = (size_t)chunk * NI + (size_t)b * 2048 + c;
#pragma unroll
    for (int s = 0; s < 16; ++s) {
        Pbuf[ob + (size_t)s * 8192] = exp2f(As2[s] * cumdt);  // prod of a over chunk
        Sbuf[ob + (size_t)s * 8192] = S[s];
    }
}

// serial fold of 32 chunk carries per (b,c,s); emits chunk-initial h
__global__ __launch_bounds__(256) void scan_comb(
    const float* __restrict__ Pbuf, const float* __restrict__ Sbuf,
    float* __restrict__ Hbuf)
{
    const int i = blockIdx.x * 256 + threadIdx.x;   // 0..NI-1 (= s*8192 + bc)
    float hi = 0.f;
#pragma unroll
    for (int k = 0; k < NCH; ++k) {
        Hbuf[(size_t)k * NI + i] = hi;
        hi = Sbuf[(size_t)k * NI + i] + Pbuf[(size_t)k * NI + i] * hi;
    }
}

// pass 2: replay chunk from h_init, y = (sum_s h*C + u*D) * silu(z), in-place over z
__global__ __launch_bounds__(256) void scan_p2(
    const _Float16* __restrict__ dt, const ushort_t* __restrict__ u,
    const float* __restrict__ BC, const float* __restrict__ A_log,
    const float* __restrict__ D_skip, const float* __restrict__ Hbuf,
    ushort_t* __restrict__ zy)
{
    __shared__ float sBC[CH * 32];
    const int tid   = threadIdx.x;
    const int blk   = blockIdx.x;
    const int chunk = blk >> 5;
    const int b     = (blk >> 3) & 3;
    const int c     = ((blk & 7) << 8) + tid;
    const size_t base = (size_t)b * 2048 + chunk * CH;

    {
        const float4* src = (const float4*)(BC + base * 32);
        float4* dst = (float4*)sBC;
        dst[tid]       = src[tid];
        dst[tid + 256] = src[tid + 256];
    }
    float As2[16], h[16];
#pragma unroll
    for (int s = 0; s < 16; ++s) As2[s] = -__expf(A_log[c * 16 + s]) * 1.44269504f;
    const float Dsk = D_skip[c];
    const size_t ob = (size_t)chunk * NI + (size_t)b * 2048 + c;
#pragma unroll
    for (int s = 0; s < 16; ++s) h[s] = Hbuf[ob + (size_t)s * 8192];
    __syncthreads();

    for (int t = 0; t < CH; ++t) {
        const size_t r = base + t;
        float dtv = (float)dt[r * 2048 + c];
        float uv  = bf2f(u[r * 2048 + c]);
        float zv  = bf2f(zy[r * 2048 + c]);
        float ct  = dtv * uv;
        float p0 = 0.f, p1 = 0.f, p2 = 0.f, p3 = 0.f;
#pragma unroll
        for (int s = 0; s < 16; s += 4) {
            float a0 = exp2f(dtv * As2[s]);
            float a1 = exp2f(dtv * As2[s + 1]);
            float a2 = exp2f(dtv * As2[s + 2]);
            float a3 = exp2f(dtv * As2[s + 3]);
            h[s]     = fmaf(h[s],     a0, ct * sBC[t * 32 + s]);
            h[s + 1] = fmaf(h[s + 1], a1, ct * sBC[t * 32 + s + 1]);
            h[s + 2] = fmaf(h[s + 2], a2, ct * sBC[t * 32 + s + 2]);
            h[s + 3] = fmaf(h[s + 3], a3, ct * sBC[t * 32 + s + 3]);
            p0 = fmaf(h[s],     sBC[t * 32 + 16 + s],     p0);
            p1 = fmaf(h[s + 1], sBC[t * 32 + 16 + s + 1], p1);
            p2 = fmaf(h[s + 2], sBC[t * 32 + 16 + s + 2], p2);
            p3 = fmaf(h[s + 3], sBC[t * 32 + 16 + s + 3], p3);
        }
        float p = (p0 + p1) + (p2 + p3);
        float g = zv / (1.f + __expf(-zv));
        float yv = (p + uv * Dsk) * g;
        zy[r * 2048 + c] = f2bf(yv);
    }
}

extern "C" void kernel_launch(void* const* d_in, const int* in_sizes, int n_in,
                              void* d_out, int out_size, void* d_ws, size_t ws_size,
                              hipStream_t stream)
{
    const float* x      = (const float*)d_in[0];   // (4,2048,1024)
    const float* W_in   = (const float*)d_in[1];   // (4096,1024)
    const float* conv_w = (const float*)d_in[2];   // (2048,4)
    const float* conv_b = (const float*)d_in[3];   // (2048,)
    const float* W_xp   = (const float*)d_in[4];   // (96,2048)
    const float* W_dt   = (const float*)d_in[5];   // (2048,64)
    const float* b_dt   = (const float*)d_in[6];   // (2048,)
    const float* A_log  = (const float*)d_in[7];   // (2048,16)
    const float* D_skip = (const float*)d_in[8];   // (2048,)
    const float* W_out  = (const float*)d_in[9];   // (1024,2048)

    char* ws = (char*)d_ws;
    const size_t MB = 1024 * 1024;
    // phase 1: xi 0-32, xw 32-48, Wib 48-56
    // GEMM3 split-K partials Pg at 32-44.6 (xw dead by then, Pb written later)
    // after GEMM4: dt(fp16) 0-32; scan: Pb 32-48, Sb 48-64
    ushort_t*  xi  = (ushort_t*)(ws);
    ushort_t*  xw  = (ushort_t*)(ws + 32 * MB);
    ushort_t*  Wib = (ushort_t*)(ws + 48 * MB);
    _Float16*  dt  = (_Float16*)(ws);
    float*     Pg  = (float*)(ws + 32 * MB);       // 12.6MB split-K partials
    float*     Pb  = (float*)(ws + 32 * MB);
    float*     Sb  = (float*)(ws + 48 * MB);
    ushort_t*  z   = (ushort_t*)(ws + 64 * MB);    // 32MB
    ushort_t*  u   = (ushort_t*)(ws + 96 * MB);    // 32MB
    ushort_t*  dbl = (ushort_t*)(ws + 128 * MB);   // 1.5MB
    ushort_t*  Wxb = (ushort_t*)(ws + 130 * MB);
    ushort_t*  Wdb = (ushort_t*)(ws + 131 * MB);
    ushort_t*  Wob = (ushort_t*)(ws + 132 * MB);   // 4MB
    float*     BCf = (float*)(ws + 137 * MB);      // 1MB
    float*     Hb  = (float*)(ws + 138 * MB);      // 16MB -> ends 154MB

    // 0) all fp32 -> bf16 casts in one kernel
    cast_all<<<14656, 256, 0, stream>>>(x, xw, W_in, Wib, W_xp, Wxb, W_dt, Wdb, W_out, Wob);

    // 1) xz = x @ W_in^T : M=8192, N=4096, K=1024 -> xi bf16 | z bf16
    gemm_bt<0><<<dim3(64, 32), 256, 0, stream>>>(xw, 1024, Wib, 1024, 1024, 4096, 2048,
                                                 nullptr, xi, z, nullptr);
    // 2) u = silu(conv(xi)+b)
    conv_silu_k<<<16384, 256, 0, stream>>>(xi, conv_w, conv_b, u);
    // 3) dbl = u @ W_xproj^T, split-K x4 -> fp32 partials, then combine
    gemm_bt<4><<<dim3(64, 4), 256, 0, stream>>>(u, 2048, Wxb, 2048, 512, 96, 96,
                                                Pg, nullptr, nullptr, nullptr);
    comb3<<<3072, 256, 0, stream>>>(Pg, dbl, BCf);
    // 4) dt = softplus(dbl[:, :64] @ W_dt^T + b_dt) -> fp16 (overlays xi)
    gemm_bt<2><<<dim3(64, 16), 256, 0, stream>>>(dbl, 96, Wdb, 64, 64, 2048, 2048,
                                                 nullptr, (ushort_t*)dt, nullptr, b_dt);
    // 5) chunked parallel scan + gating; y overwrites z (bf16)
    scan_p1<<<1024, 256, 0, stream>>>(dt, u, BCf, A_log, Pb, Sb);
    scan_comb<<<512, 256, 0, stream>>>(Pb, Sb, Hb);
    scan_p2<<<1024, 256, 0, stream>>>(dt, u, BCf, A_log, D_skip, Hb, z);
    // 6) out = y @ W_out^T : M=8192, N=1024, K=2048 -> fp32 d_out
    gemm_bt<3><<<dim3(64, 8), 256, 0, stream>>>(z, 2048, Wob, 2048, 2048, 1024, 1024,
                                                (float*)d_out, nullptr, nullptr, nullptr);
}

// Round 7
// 462.614 us; speedup vs baseline: 2.6959x; 1.1473x over previous
//
#include <hip/hip_runtime.h>

#define AS1 __attribute__((address_space(1)))
#define AS3 __attribute__((address_space(3)))

typedef unsigned short ushort_t;
typedef __attribute__((ext_vector_type(8))) short short8;
typedef __attribute__((ext_vector_type(4))) float floatx4;

__device__ __forceinline__ float bf2f(ushort_t h) {
    return __uint_as_float(((unsigned int)h) << 16);
}
__device__ __forceinline__ ushort_t f2bf(float f) {
    unsigned int u = __float_as_uint(f);
    u += 0x7fffu + ((u >> 16) & 1u);   // RNE
    return (ushort_t)(u >> 16);
}

// single merged fp32 -> bf16 cast over 5 arrays (float4 granularity)
__global__ __launch_bounds__(256) void cast_all(
    const float* __restrict__ s0, ushort_t* __restrict__ d0,   // x      2097152 f4
    const float* __restrict__ s1, ushort_t* __restrict__ d1,   // W_in   1048576
    const float* __restrict__ s2, ushort_t* __restrict__ d2,   // W_xp     49152
    const float* __restrict__ s3, ushort_t* __restrict__ d3,   // W_dt     32768
    const float* __restrict__ s4, ushort_t* __restrict__ d4)   // W_out   524288
{
    int i = blockIdx.x * 256 + threadIdx.x;
    const float* src; ushort_t* dst; int off;
    if      (i < 2097152) { src = s0; dst = d0; off = i; }
    else if (i < 3145728) { src = s1; dst = d1; off = i - 2097152; }
    else if (i < 3194880) { src = s2; dst = d2; off = i - 3145728; }
    else if (i < 3227648) { src = s3; dst = d3; off = i - 3194880; }
    else                  { src = s4; dst = d4; off = i - 3227648; }
    float4 v = ((const float4*)src)[off];
    ((ushort4*)dst)[off] = make_ushort4(f2bf(v.x), f2bf(v.y), f2bf(v.z), f2bf(v.w));
}

// C[m,n] = sum_k A[m,k]*B[n,k];  A: M x lda bf16, B: N x ldb bf16.
// 128x128 tile, BK=64, XOR-swizzled LDS (granule hh = (g&7)^(row&7)) ->
// ds_read_b128 is 2-way-conflict max (free). 4 waves, wave = 64x64.
// MODE 0: cols<2048 -> outH (xi bf16), cols>=2048 -> outH2 (z bf16)
// MODE 2: softplus(acc + biasF[col]) -> fp16 (bits in outH)
// MODE 3: fp32 store col<Nact (final output)
// MODE 4: split-K partial (seg = blockIdx.y, n0 = 0): fp32 partial col<96
template <int MODE>
__global__ __launch_bounds__(256) void gemm_bt(
    const ushort_t* __restrict__ A, int lda,
    const ushort_t* __restrict__ B, int ldb,
    int K, int Nact, int ldc,
    float* __restrict__ outF, ushort_t* __restrict__ outH,
    ushort_t* __restrict__ outH2, const float* __restrict__ biasF)
{
    constexpr int BM = 128, BN = 128, BK = 64;
    __shared__ ushort_t sA[BM * BK];   // 16 KB, granule(16B)-swizzled
    __shared__ ushort_t sB[BN * BK];
    const int tid  = threadIdx.x;
    const int m0   = blockIdx.x * BM;
    const int seg  = (MODE == 4) ? blockIdx.y : 0;
    const int n0   = (MODE == 4) ? 0 : blockIdx.y * BN;
    if (MODE == 4) { A += seg * 512; B += seg * 512; }
    const int lane = tid & 63, wave = tid >> 6;
    const int wm   = (wave & 1) * 64, wn = (wave >> 1) * 64;
    const int lm   = lane & 15, quad = lane >> 4;
    const int lm7  = lane & 7;

    floatx4 acc[4][4];
#pragma unroll
    for (int i = 0; i < 4; ++i)
#pragma unroll
        for (int j = 0; j < 4; ++j)
            acc[i][j] = (floatx4){0.f, 0.f, 0.f, 0.f};

    for (int k0 = 0; k0 < K; k0 += BK) {
        __syncthreads();
#pragma unroll
        for (int r = 0; r < 4; ++r) {
            int g   = r * 256 + tid;            // granule index 0..1023
            int row = g >> 3;
            int hh  = (g & 7) ^ (row & 7);      // swizzled 16B-granule in row
            int col = k0 + hh * 8;
            const ushort_t* gA = A + (size_t)(m0 + row) * lda + col;
            __builtin_amdgcn_global_load_lds((const AS1 void*)gA, (AS3 void*)(&sA[g * 8]), 16, 0, 0);
            int rowB = n0 + row;
            if (rowB >= Nact) rowB = Nact - 1;  // clamp; garbage cols discarded in epilogue
            const ushort_t* gB = B + (size_t)rowB * ldb + col;
            __builtin_amdgcn_global_load_lds((const AS1 void*)gB, (AS3 void*)(&sB[g * 8]), 16, 0, 0);
        }
        __syncthreads();

#pragma unroll
        for (int s = 0; s < 2; ++s) {
            short8 af[4], bfr[4];
#pragma unroll
            for (int i = 0; i < 4; ++i) {
                int row = wm + i * 16 + lm;
                int gr  = row * 8 + ((s * 4 + quad) ^ lm7);
                af[i] = *(const short8*)&sA[gr * 8];
            }
#pragma unroll
            for (int j = 0; j < 4; ++j) {
                int row = wn + j * 16 + lm;
                int gr  = row * 8 + ((s * 4 + quad) ^ lm7);
                bfr[j] = *(const short8*)&sB[gr * 8];
            }
#pragma unroll
            for (int i = 0; i < 4; ++i)
#pragma unroll
                for (int j = 0; j < 4; ++j)
                    acc[i][j] = __builtin_amdgcn_mfma_f32_16x16x32_bf16(af[i], bfr[j], acc[i][j], 0, 0, 0);
        }
    }

#pragma unroll
    for (int i = 0; i < 4; ++i) {
#pragma unroll
        for (int j = 0; j < 4; ++j) {
#pragma unroll
            for (int r = 0; r < 4; ++r) {
                int row = m0 + wm + i * 16 + quad * 4 + r;
                int col = n0 + wn + j * 16 + lm;
                float v = acc[i][j][r];
                if (MODE == 0) {
                    if (col < 2048) outH[(size_t)row * 2048 + col] = f2bf(v);
                    else            outH2[(size_t)row * 2048 + (col - 2048)] = f2bf(v);
                } else if (MODE == 2) {
                    float x  = v + biasF[col];
                    float sp = (x > 20.f) ? x : log1pf(__expf(x));
                    _Float16 hv = (_Float16)sp;
                    outH[(size_t)row * ldc + col] = *(ushort_t*)&hv;
                } else if (MODE == 3) {
                    if (col < Nact) outF[(size_t)row * ldc + col] = v;
                } else if (MODE == 4) {
                    if (col < 96)
                        outF[(size_t)seg * 786432 + (size_t)row * 96 + col] = v;
                }
            }
        }
    }
}

// combine split-K partials: dbl bf16 (8192x96) + B/C cols fp32 -> BCf (8192x32)
__global__ __launch_bounds__(256) void comb3(
    const float* __restrict__ Pg, ushort_t* __restrict__ dbl,
    float* __restrict__ BCf)
{
    int i = blockIdx.x * 256 + threadIdx.x;   // 0..786431
    float v = Pg[i] + Pg[i + 786432] + Pg[i + 2 * 786432] + Pg[i + 3 * 786432];
    dbl[i] = f2bf(v);
    int col = i % 96;
    if (col >= 64) BCf[(size_t)(i / 96) * 32 + (col - 64)] = v;
}

// u = silu(depthwise_causal_conv4(xi) + conv_b); 4 outputs along l per thread
__global__ __launch_bounds__(256) void conv_silu_k(
    const ushort_t* __restrict__ xi, const float* __restrict__ conv_w,
    const float* __restrict__ conv_b, ushort_t* __restrict__ u)
{
    int idx = blockIdx.x * 256 + threadIdx.x;  // 0..4194303
    int c   = idx & 2047;
    int lg  = idx >> 11;        // 0..2047
    int b   = lg >> 9;
    int l0  = (lg & 511) * 4;
    const size_t base = ((size_t)b * 2048 + l0) * 2048 + c;

    float w0 = conv_w[c * 4], w1 = conv_w[c * 4 + 1],
          w2 = conv_w[c * 4 + 2], w3 = conv_w[c * 4 + 3];
    float bias = conv_b[c];

    float xv[7];
#pragma unroll
    for (int j = 0; j < 3; ++j)
        xv[j] = (l0 - 3 + j >= 0) ? bf2f(xi[base + (j - 3) * 2048]) : 0.f;
#pragma unroll
    for (int j = 3; j < 7; ++j)
        xv[j] = bf2f(xi[base + (j - 3) * 2048]);

#pragma unroll
    for (int i = 0; i < 4; ++i) {
        float acc = bias + w0 * xv[i] + w1 * xv[i + 1] + w2 * xv[i + 2] + w3 * xv[i + 3];
        float s = acc / (1.f + __expf(-acc));
        u[base + i * 2048] = f2bf(s);
    }
}

// ---- chunked 2-pass parallel scan ------------------------------------------
// thread = (b, c, chunk); 16 states in registers; 32 chunks x 64 steps.
// grid: 1024 blocks = chunk(32) x b(4) x cblk(8); block = 256 threads over c.
// B/C read from global with WAVE-UNIFORM addresses -> compiler emits scalar
// s_load through the constant cache (free on VALU/LDS pipes). [R6: LDS staging
// of B/C regressed p2 83->123 us (spills + ds_read pipe); reverted.]
// carry layout: [chunk][s][b*2048+c] -> fully coalesced
constexpr int CH  = 64;
constexpr int NCH = 32;
constexpr int NI  = 4 * 2048 * 16;  // 131072

__global__ __launch_bounds__(256) void scan_p1(
    const _Float16* __restrict__ dt, const ushort_t* __restrict__ u,
    const float* __restrict__ BC, const float* __restrict__ A_log,
    float* __restrict__ Pbuf, float* __restrict__ Sbuf)
{
    const int tid   = threadIdx.x;
    const int blk   = blockIdx.x;
    const int chunk = blk >> 5;
    const int b     = (blk >> 3) & 3;
    const int c     = ((blk & 7) << 8) + tid;
    const size_t base = (size_t)b * 2048 + chunk * CH;

    float As[16];
#pragma unroll
    for (int s = 0; s < 16; ++s) As[s] = -__expf(A_log[c * 16 + s]);

    float S[16];
#pragma unroll
    for (int s = 0; s < 16; ++s) S[s] = 0.f;
    float cumdt = 0.f;

    for (int t = 0; t < CH; ++t) {
        const size_t r = base + t;
        float dtv = (float)dt[r * 2048 + c];
        float uv  = bf2f(u[r * 2048 + c]);
        float ct  = dtv * uv;
        cumdt += dtv;
#pragma unroll
        for (int s = 0; s < 16; ++s) {
            float a = __expf(dtv * As[s]);
            S[s] = fmaf(S[s], a, ct * BC[r * 32 + s]);
        }
    }
    const size_t ob = (size_t)chunk * NI + (size_t)b * 2048 + c;
#pragma unroll
    for (int s = 0; s < 16; ++s) {
        Pbuf[ob + (size_t)s * 8192] = __expf(As[s] * cumdt);  // prod of a over chunk
        Sbuf[ob + (size_t)s * 8192] = S[s];
    }
}

// serial fold of 32 chunk carries per (b,c,s); emits chunk-initial h
__global__ __launch_bounds__(256) void scan_comb(
    const float* __restrict__ Pbuf, const float* __restrict__ Sbuf,
    float* __restrict__ Hbuf)
{
    const int i = blockIdx.x * 256 + threadIdx.x;   // 0..NI-1 (= s*8192 + bc)
    float hi = 0.f;
#pragma unroll
    for (int k = 0; k < NCH; ++k) {
        Hbuf[(size_t)k * NI + i] = hi;
        hi = Sbuf[(size_t)k * NI + i] + Pbuf[(size_t)k * NI + i] * hi;
    }
}

// pass 2: replay chunk from h_init, y = (sum_s h*C + u*D) * silu(z), in-place over z
__global__ __launch_bounds__(256) void scan_p2(
    const _Float16* __restrict__ dt, const ushort_t* __restrict__ u,
    const float* __restrict__ BC, const float* __restrict__ A_log,
    const float* __restrict__ D_skip, const float* __restrict__ Hbuf,
    ushort_t* __restrict__ zy)
{
    const int tid   = threadIdx.x;
    const int blk   = blockIdx.x;
    const int chunk = blk >> 5;
    const int b     = (blk >> 3) & 3;
    const int c     = ((blk & 7) << 8) + tid;
    const size_t base = (size_t)b * 2048 + chunk * CH;

    float As[16], h[16];
#pragma unroll
    for (int s = 0; s < 16; ++s) As[s] = -__expf(A_log[c * 16 + s]);
    const float Dsk = D_skip[c];
    const size_t ob = (size_t)chunk * NI + (size_t)b * 2048 + c;
#pragma unroll
    for (int s = 0; s < 16; ++s) h[s] = Hbuf[ob + (size_t)s * 8192];

    for (int t = 0; t < CH; ++t) {
        const size_t r = base + t;
        float dtv = (float)dt[r * 2048 + c];
        float uv  = bf2f(u[r * 2048 + c]);
        float zv  = bf2f(zy[r * 2048 + c]);
        float ct  = dtv * uv;
        float p0 = 0.f, p1 = 0.f, p2 = 0.f, p3 = 0.f;
#pragma unroll
        for (int s = 0; s < 16; s += 4) {
            float a0 = __expf(dtv * As[s]);
            float a1 = __expf(dtv * As[s + 1]);
            float a2 = __expf(dtv * As[s + 2]);
            float a3 = __expf(dtv * As[s + 3]);
            h[s]     = fmaf(h[s],     a0, ct * BC[r * 32 + s]);
            h[s + 1] = fmaf(h[s + 1], a1, ct * BC[r * 32 + s + 1]);
            h[s + 2] = fmaf(h[s + 2], a2, ct * BC[r * 32 + s + 2]);
            h[s + 3] = fmaf(h[s + 3], a3, ct * BC[r * 32 + s + 3]);
            p0 = fmaf(h[s],     BC[r * 32 + 16 + s],     p0);
            p1 = fmaf(h[s + 1], BC[r * 32 + 16 + s + 1], p1);
            p2 = fmaf(h[s + 2], BC[r * 32 + 16 + s + 2], p2);
            p3 = fmaf(h[s + 3], BC[r * 32 + 16 + s + 3], p3);
        }
        float p = (p0 + p1) + (p2 + p3);
        float g = zv / (1.f + __expf(-zv));
        float yv = (p + uv * Dsk) * g;
        zy[r * 2048 + c] = f2bf(yv);
    }
}

extern "C" void kernel_launch(void* const* d_in, const int* in_sizes, int n_in,
                              void* d_out, int out_size, void* d_ws, size_t ws_size,
                              hipStream_t stream)
{
    const float* x      = (const float*)d_in[0];   // (4,2048,1024)
    const float* W_in   = (const float*)d_in[1];   // (4096,1024)
    const float* conv_w = (const float*)d_in[2];   // (2048,4)
    const float* conv_b = (const float*)d_in[3];   // (2048,)
    const float* W_xp   = (const float*)d_in[4];   // (96,2048)
    const float* W_dt   = (const float*)d_in[5];   // (2048,64)
    const float* b_dt   = (const float*)d_in[6];   // (2048,)
    const float* A_log  = (const float*)d_in[7];   // (2048,16)
    const float* D_skip = (const float*)d_in[8];   // (2048,)
    const float* W_out  = (const float*)d_in[9];   // (1024,2048)

    char* ws = (char*)d_ws;
    const size_t MB = 1024 * 1024;
    // phase 1: xi 0-32, xw 32-48, Wib 48-56
    // GEMM3 split-K partials Pg at 32-44.6 (xw dead by then)
    // after GEMM4: dt(fp16) 0-32; scan: Pb 32-48, Sb 48-64
    ushort_t*  xi  = (ushort_t*)(ws);
    ushort_t*  xw  = (ushort_t*)(ws + 32 * MB);
    ushort_t*  Wib = (ushort_t*)(ws + 48 * MB);
    _Float16*  dt  = (_Float16*)(ws);
    float*     Pg  = (float*)(ws + 32 * MB);       // 12.6MB split-K partials
    float*     Pb  = (float*)(ws + 32 * MB);
    float*     Sb  = (float*)(ws + 48 * MB);
    ushort_t*  z   = (ushort_t*)(ws + 64 * MB);    // 32MB
    ushort_t*  u   = (ushort_t*)(ws + 96 * MB);    // 32MB
    ushort_t*  dbl = (ushort_t*)(ws + 128 * MB);   // 1.5MB
    ushort_t*  Wxb = (ushort_t*)(ws + 130 * MB);
    ushort_t*  Wdb = (ushort_t*)(ws + 131 * MB);
    ushort_t*  Wob = (ushort_t*)(ws + 132 * MB);   // 4MB
    float*     BCf = (float*)(ws + 137 * MB);      // 1MB
    float*     Hb  = (float*)(ws + 138 * MB);      // 16MB -> ends 154MB

    // 0) all fp32 -> bf16 casts in one kernel
    cast_all<<<14656, 256, 0, stream>>>(x, xw, W_in, Wib, W_xp, Wxb, W_dt, Wdb, W_out, Wob);

    // 1) xz = x @ W_in^T : M=8192, N=4096, K=1024 -> xi bf16 | z bf16
    gemm_bt<0><<<dim3(64, 32), 256, 0, stream>>>(xw, 1024, Wib, 1024, 1024, 4096, 2048,
                                                 nullptr, xi, z, nullptr);
    // 2) u = silu(conv(xi)+b)
    conv_silu_k<<<16384, 256, 0, stream>>>(xi, conv_w, conv_b, u);
    // 3) dbl = u @ W_xproj^T, split-K x4 -> fp32 partials, then combine
    gemm_bt<4><<<dim3(64, 4), 256, 0, stream>>>(u, 2048, Wxb, 2048, 512, 96, 96,
                                                Pg, nullptr, nullptr, nullptr);
    comb3<<<3072, 256, 0, stream>>>(Pg, dbl, BCf);
    // 4) dt = softplus(dbl[:, :64] @ W_dt^T + b_dt) -> fp16 (overlays xi)
    gemm_bt<2><<<dim3(64, 16), 256, 0, stream>>>(dbl, 96, Wdb, 64, 64, 2048, 2048,
                                                 nullptr, (ushort_t*)dt, nullptr, b_dt);
    // 5) chunked parallel scan + gating; y overwrites z (bf16)
    scan_p1<<<1024, 256, 0, stream>>>(dt, u, BCf, A_log, Pb, Sb);
    scan_comb<<<512, 256, 0, stream>>>(Pb, Sb, Hb);
    scan_p2<<<1024, 256, 0, stream>>>(dt, u, BCf, A_log, D_skip, Hb, z);
    // 6) out = y @ W_out^T : M=8192, N=1024, K=2048 -> fp32 d_out
    gemm_bt<3><<<dim3(64, 8), 256, 0, stream>>>(z, 2048, Wob, 2048, 2048, 1024, 1024,
                                                (float*)d_out, nullptr, nullptr, nullptr);
}